// Round 5
// baseline (359.454 us; speedup 1.0000x reference)
//
#include <hip/hip_runtime.h>
#include <math.h>

#define BSZ 4096
#define DIM 256
// 20 * log2(e): rows are pre-scaled by sqrt(20*log2e)/||row|| so the MFMA
// emits u = score*log2e; exp2(u - SC20L2E) == exp(score - 20) exactly.
#define SC20L2E 28.853900817779268f
#define NTILE 4096   // 32 x 32 x 4 pair-tile blocks

#if __has_builtin(__builtin_amdgcn_exp2f)
#define EXP2F(x) __builtin_amdgcn_exp2f(x)
#else
#define EXP2F(x) exp2f(x)
#endif

typedef float floatx4 __attribute__((ext_vector_type(4)));

__device__ __forceinline__ void async_cp16(void* lds, const void* g) {
    __builtin_amdgcn_global_load_lds(
        (__attribute__((address_space(1))) unsigned int*)(unsigned long long)g,
        (__attribute__((address_space(3))) unsigned int*)lds,
        16, 0, 0);
}

// One wave per row index: load row r of all 4 matrices once.
// Outputs: fp8 e4m3 rows pre-scaled by sqrt(20*log2e)/||row||, fp32 diagonal
// scores for the 4 pairs; zeroes rowsum/colsum/cnt (first 64 blocks).
__global__ __launch_bounds__(256)
void prep_kernel(const float* __restrict__ a0, const float* __restrict__ a1,
                 const float* __restrict__ a2, const float* __restrict__ a3,
                 unsigned char* __restrict__ f8, float* __restrict__ diag,
                 float* __restrict__ rowsum, float* __restrict__ colsum,
                 unsigned int* __restrict__ cnt) {
    const float* srcs[4] = {a0, a1, a2, a3};
    int w = threadIdx.x >> 6, lane = threadIdx.x & 63;
    int row = blockIdx.x * 4 + w;

    float4 v[4];
    float red[8];
    #pragma unroll
    for (int m = 0; m < 4; m++) {
        v[m] = ((const float4*)(srcs[m] + (size_t)row * DIM))[lane];
        red[m] = v[m].x * v[m].x + v[m].y * v[m].y + v[m].z * v[m].z + v[m].w * v[m].w;
    }
    // pair dots: (0,1) (0,2) (1,2) (1,3)
    red[4] = v[0].x * v[1].x + v[0].y * v[1].y + v[0].z * v[1].z + v[0].w * v[1].w;
    red[5] = v[0].x * v[2].x + v[0].y * v[2].y + v[0].z * v[2].z + v[0].w * v[2].w;
    red[6] = v[1].x * v[2].x + v[1].y * v[2].y + v[1].z * v[2].z + v[1].w * v[2].w;
    red[7] = v[1].x * v[3].x + v[1].y * v[3].y + v[1].z * v[3].z + v[1].w * v[3].w;

    #pragma unroll
    for (int i = 0; i < 8; i++) {
        #pragma unroll
        for (int s = 32; s; s >>= 1) red[i] += __shfl_xor(red[i], s, 64);
    }

    float rinv[4];
    #pragma unroll
    for (int m = 0; m < 4; m++) rinv[m] = rsqrtf(fmaxf(red[m], 1e-24f));

    const float sq = sqrtf(SC20L2E);
    #pragma unroll
    for (int m = 0; m < 4; m++) {
        float sc = sq * rinv[m];
        int pk = __builtin_amdgcn_cvt_pk_fp8_f32(v[m].x * sc, v[m].y * sc, 0, false);
        pk = __builtin_amdgcn_cvt_pk_fp8_f32(v[m].z * sc, v[m].w * sc, pk, true);
        ((unsigned int*)(f8 + (size_t)m * BSZ * DIM))[row * 64 + lane] = (unsigned int)pk;
    }

    if (lane == 0) {
        diag[0 * BSZ + row] = red[4] * 20.0f * rinv[0] * rinv[1];
        diag[1 * BSZ + row] = red[5] * 20.0f * rinv[0] * rinv[2];
        diag[2 * BSZ + row] = red[6] * 20.0f * rinv[1] * rinv[2];
        diag[3 * BSZ + row] = red[7] * 20.0f * rinv[1] * rinv[3];
    }
    if (blockIdx.x < 64) {
        int idx = blockIdx.x * 256 + threadIdx.x;
        rowsum[idx] = 0.f;
        colsum[idx] = 0.f;
        if (idx == 0) *cnt = 0u;
    }
}

// 128x128 tile of exp(score-20) per block (pair = blockIdx.z), fp8 MFMA.
// Full-K LDS (64 KB, 2 blocks/CU). XOR chunk swizzle: chunk(row,kq) lives at
// byte row*256 + (((kq ^ row)&15)<<4)  -> fragment address = Q ^ (ks<<5) with
// Q hoisted (1 v_xor per ds_read). Last-finishing block folds the final
// log-sum reduction (agent-scope atomic loads for cross-XCD safety).
__global__ __launch_bounds__(256, 2)
void pair_scores_kernel(const unsigned char* __restrict__ f8,
                        float* __restrict__ rowsum,
                        float* __restrict__ colsum,
                        const float* __restrict__ diag,
                        unsigned int* __restrict__ cnt,
                        float* __restrict__ out) {
    const int PX[4] = {0, 0, 1, 1};
    const int PY[4] = {1, 2, 2, 3};
    int p = blockIdx.z;
    const unsigned char* Xb = f8 + (size_t)PX[p] * BSZ * DIM;
    const unsigned char* Yb = f8 + (size_t)PY[p] * BSZ * DIM;
    float* rs = rowsum + p * BSZ;
    float* cs = colsum + p * BSZ;

    __shared__ __align__(16) unsigned char smem[65536];

    int tid  = threadIdx.x;
    int lane = tid & 63;
    int w    = tid >> 6;
    int wm = w >> 1, wn = w & 1;
    int q = lane >> 4, l = lane & 15;
    int bi = blockIdx.x * 128, bj = blockIdx.y * 128;

    // ---- stage both full-K panels (2048 16-B chunks each), XOR swizzle ----
    #pragma unroll
    for (int i = 0; i < 8; i++) {
        int sb  = i * 256 + w * 64;
        int s   = sb + lane;
        int row = s >> 4;
        int kq  = (s ^ row) & 15;
        async_cp16(smem + sb * 16,         Xb + (size_t)(bi + row) * 256 + kq * 16);
        async_cp16(smem + 32768 + sb * 16, Yb + (size_t)(bj + row) * 256 + kq * 16);
    }
    __syncthreads();  // single drain for the whole block

    // Hoisted fragment base addresses: Q = row*256 + qb + (((qh^row)&15)<<4)
    int qh = q >> 1, qb = (q & 1) * 8;
    unsigned qa[4], qbv[4];
    #pragma unroll
    for (int t = 0; t < 4; t++) {
        int ra = wm * 64 + t * 16 + l;
        int rb = wn * 64 + t * 16 + l;
        qa[t] = (unsigned)(ra * 256 + qb + (((qh ^ ra) & 15) << 4));
        qbv[t] = (unsigned)(32768 + rb * 256 + qb + (((qh ^ rb) & 15) << 4));
    }

    floatx4 acc[4][4] = {};
    #pragma unroll
    for (int ks = 0; ks < 8; ks++) {
        const unsigned kx = (unsigned)(ks << 5);
        long long a[4], b[4];
        #pragma unroll
        for (int t = 0; t < 4; t++) {
            a[t] = *(const long long*)(smem + (qa[t] ^ kx));
            b[t] = *(const long long*)(smem + (qbv[t] ^ kx));
        }
        #pragma unroll
        for (int i = 0; i < 4; i++)
            #pragma unroll
            for (int j = 0; j < 4; j++)
                acc[i][j] = __builtin_amdgcn_mfma_f32_16x16x32_fp8_fp8(a[i], b[j], acc[i][j], 0, 0, 0);
    }

    // ---- epilogue: exp2 (raw v_exp_f32), butterfly reductions, atomics ----
    // C/D layout per 16x16 tile: col = l, row = q*4 + reg.
    #pragma unroll
    for (int ai = 0; ai < 4; ai++)
        #pragma unroll
        for (int bt = 0; bt < 4; bt++)
            #pragma unroll
            for (int r = 0; r < 4; r++)
                acc[ai][bt][r] = EXP2F(acc[ai][bt][r] - SC20L2E);

    // Row sums: v[t], t = ai*4+r, reduce over the 16 l-lanes; result t -> lane l==t.
    float v[16];
    #pragma unroll
    for (int ai = 0; ai < 4; ai++)
        #pragma unroll
        for (int r = 0; r < 4; r++)
            v[ai * 4 + r] = acc[ai][0][r] + acc[ai][1][r] + acc[ai][2][r] + acc[ai][3][r];

    float w1[8];
    #pragma unroll
    for (int k = 0; k < 8; k++) {
        float snd = (l & 1) ? v[2 * k] : v[2 * k + 1];
        float got = __shfl_xor(snd, 1, 64);
        w1[k] = ((l & 1) ? v[2 * k + 1] : v[2 * k]) + got;
    }
    float w2[4];
    #pragma unroll
    for (int m = 0; m < 4; m++) {
        float snd = ((l >> 1) & 1) ? w1[2 * m] : w1[2 * m + 1];
        float got = __shfl_xor(snd, 2, 64);
        w2[m] = (((l >> 1) & 1) ? w1[2 * m + 1] : w1[2 * m]) + got;
    }
    float w3[2];
    #pragma unroll
    for (int n = 0; n < 2; n++) {
        float snd = ((l >> 2) & 1) ? w2[2 * n] : w2[2 * n + 1];
        float got = __shfl_xor(snd, 4, 64);
        w3[n] = (((l >> 2) & 1) ? w2[2 * n + 1] : w2[2 * n]) + got;
    }
    {
        float snd = ((l >> 3) & 1) ? w3[0] : w3[1];
        float got = __shfl_xor(snd, 8, 64);
        float wr = (((l >> 3) & 1) ? w3[1] : w3[0]) + got;
        atomicAdd(&rs[bi + wm * 64 + ((l >> 2) << 4) + q * 4 + (l & 3)], wr);
    }

    // Col sums: c4[bt], reduce over the 4 q-groups; result bt -> q==bt.
    float c4[4];
    #pragma unroll
    for (int bt = 0; bt < 4; bt++) {
        float s = 0.f;
        #pragma unroll
        for (int ai = 0; ai < 4; ai++)
            #pragma unroll
            for (int r = 0; r < 4; r++) s += acc[ai][bt][r];
        c4[bt] = s;
    }
    float e0, e1, fsum;
    {
        float snd = (q & 1) ? c4[0] : c4[1];
        float got = __shfl_xor(snd, 16, 64);
        e0 = ((q & 1) ? c4[1] : c4[0]) + got;
    }
    {
        float snd = (q & 1) ? c4[2] : c4[3];
        float got = __shfl_xor(snd, 16, 64);
        e1 = ((q & 1) ? c4[3] : c4[2]) + got;
    }
    {
        float snd = ((q >> 1) & 1) ? e0 : e1;
        float got = __shfl_xor(snd, 32, 64);
        fsum = (((q >> 1) & 1) ? e1 : e0) + got;
    }
    atomicAdd(&cs[bj + wn * 64 + (q << 4) + l], fsum);

    // ---- last-done block: final reduction ----
    __threadfence();
    __syncthreads();
    __shared__ unsigned int is_last;
    if (tid == 0) is_last = (atomicAdd(cnt, 1u) == NTILE - 1) ? 1u : 0u;
    __syncthreads();
    if (!is_last) return;
    __threadfence();  // acquire: other blocks' atomics visible

    float accf = 0.f;
    for (int idx = tid; idx < 4 * BSZ; idx += 256) {
        float rv = __hip_atomic_load(&rowsum[idx], __ATOMIC_RELAXED, __HIP_MEMORY_SCOPE_AGENT);
        float cv = __hip_atomic_load(&colsum[idx], __ATOMIC_RELAXED, __HIP_MEMORY_SCOPE_AGENT);
        accf += 0.5f * (__logf(rv) + __logf(cv)) - diag[idx];
    }
    float* red = (float*)smem;
    red[tid] = accf;
    __syncthreads();
    for (int s = 128; s; s >>= 1) {
        if (tid < s) red[tid] += red[tid + s];
        __syncthreads();
    }
    if (tid == 0)
        out[0] = (red[0] + 20.0f * 4 * BSZ) / (BSZ * 2.0f);
}

extern "C" void kernel_launch(void* const* d_in, const int* in_sizes, int n_in,
                              void* d_out, int out_size, void* d_ws, size_t ws_size,
                              hipStream_t stream) {
    const float* in_anchor = (const float*)d_in[0];
    const float* in_pos    = (const float*)d_in[1];
    // d_in[2] (reference_anchor) intentionally unused, matching the reference.
    const float* in_rtext  = (const float*)d_in[3];
    const float* in_rvis   = (const float*)d_in[4];

    char* ws = (char*)d_ws;
    unsigned char* f8 = (unsigned char*)ws;                 // 4 * B * D fp8
    size_t f8_bytes = (size_t)4 * BSZ * DIM;
    float* rowsum = (float*)(ws + f8_bytes);                // 4 * B
    float* colsum = rowsum + 4 * BSZ;                       // 4 * B
    float* diag   = colsum + 4 * BSZ;                       // 4 * B
    unsigned int* cnt = (unsigned int*)(diag + 4 * BSZ);    // 1

    prep_kernel<<<BSZ / 4, 256, 0, stream>>>(
        in_anchor, in_pos, in_rtext, in_rvis, f8, diag, rowsum, colsum, cnt);

    pair_scores_kernel<<<dim3(BSZ / 128, BSZ / 128, 4), 256, 0, stream>>>(
        f8, rowsum, colsum, diag, cnt, (float*)d_out);
}

// Round 6
// 118.220 us; speedup vs baseline: 3.0405x; 3.0405x over previous
//
#include <hip/hip_runtime.h>
#include <math.h>

#define BSZ 4096
#define DIM 256
// 20 * log2(e): rows are pre-scaled by sqrt(20*log2e)/||row|| so the MFMA
// emits u = score*log2e; exp2(u - SC20L2E) == exp(score - 20) exactly.
#define SC20L2E 28.853900817779268f

#if __has_builtin(__builtin_amdgcn_exp2f)
#define EXP2F(x) __builtin_amdgcn_exp2f(x)
#else
#define EXP2F(x) exp2f(x)
#endif

typedef float floatx4 __attribute__((ext_vector_type(4)));

__device__ __forceinline__ void async_cp16(void* lds, const void* g) {
    __builtin_amdgcn_global_load_lds(
        (__attribute__((address_space(1))) unsigned int*)(unsigned long long)g,
        (__attribute__((address_space(3))) unsigned int*)lds,
        16, 0, 0);
}

// One wave per row index: load row r of all 4 matrices once.
// Outputs: fp8 e4m3 rows pre-scaled by sqrt(20*log2e)/||row||, fp32 diagonal
// scores for the 4 pairs; zeroes rowsum/colsum (first 64 blocks).
__global__ __launch_bounds__(256)
void prep_kernel(const float* __restrict__ a0, const float* __restrict__ a1,
                 const float* __restrict__ a2, const float* __restrict__ a3,
                 unsigned char* __restrict__ f8, float* __restrict__ diag,
                 float* __restrict__ rowsum, float* __restrict__ colsum) {
    const float* srcs[4] = {a0, a1, a2, a3};
    int w = threadIdx.x >> 6, lane = threadIdx.x & 63;
    int row = blockIdx.x * 4 + w;

    float4 v[4];
    float red[8];
    #pragma unroll
    for (int m = 0; m < 4; m++) {
        v[m] = ((const float4*)(srcs[m] + (size_t)row * DIM))[lane];
        red[m] = v[m].x * v[m].x + v[m].y * v[m].y + v[m].z * v[m].z + v[m].w * v[m].w;
    }
    // pair dots: (0,1) (0,2) (1,2) (1,3)
    red[4] = v[0].x * v[1].x + v[0].y * v[1].y + v[0].z * v[1].z + v[0].w * v[1].w;
    red[5] = v[0].x * v[2].x + v[0].y * v[2].y + v[0].z * v[2].z + v[0].w * v[2].w;
    red[6] = v[1].x * v[2].x + v[1].y * v[2].y + v[1].z * v[2].z + v[1].w * v[2].w;
    red[7] = v[1].x * v[3].x + v[1].y * v[3].y + v[1].z * v[3].z + v[1].w * v[3].w;

    #pragma unroll
    for (int i = 0; i < 8; i++) {
        #pragma unroll
        for (int s = 32; s; s >>= 1) red[i] += __shfl_xor(red[i], s, 64);
    }

    float rinv[4];
    #pragma unroll
    for (int m = 0; m < 4; m++) rinv[m] = rsqrtf(fmaxf(red[m], 1e-24f));

    const float sq = sqrtf(SC20L2E);
    #pragma unroll
    for (int m = 0; m < 4; m++) {
        float sc = sq * rinv[m];
        int pk = __builtin_amdgcn_cvt_pk_fp8_f32(v[m].x * sc, v[m].y * sc, 0, false);
        pk = __builtin_amdgcn_cvt_pk_fp8_f32(v[m].z * sc, v[m].w * sc, pk, true);
        ((unsigned int*)(f8 + (size_t)m * BSZ * DIM))[row * 64 + lane] = (unsigned int)pk;
    }

    if (lane == 0) {
        diag[0 * BSZ + row] = red[4] * 20.0f * rinv[0] * rinv[1];
        diag[1 * BSZ + row] = red[5] * 20.0f * rinv[0] * rinv[2];
        diag[2 * BSZ + row] = red[6] * 20.0f * rinv[1] * rinv[2];
        diag[3 * BSZ + row] = red[7] * 20.0f * rinv[1] * rinv[3];
    }
    if (blockIdx.x < 64) {
        int idx = blockIdx.x * 256 + threadIdx.x;
        rowsum[idx] = 0.f;
        colsum[idx] = 0.f;
    }
}

// 128x128 tile of exp(score-20) per block (pair = blockIdx.z), fp8 MFMA.
// Full-K LDS (64 KB, 2 blocks/CU), one barrier per block. XOR chunk swizzle:
// chunk(row,kq) at byte row*256 + (((kq ^ row)&15)<<4) -> fragment address is
// Q ^ (ks<<5) with Q hoisted (1 v_xor per ds_read). No device fences.
__global__ __launch_bounds__(256)
void pair_scores_kernel(const unsigned char* __restrict__ f8,
                        float* __restrict__ rowsum,
                        float* __restrict__ colsum) {
    const int PX[4] = {0, 0, 1, 1};
    const int PY[4] = {1, 2, 2, 3};
    int p = blockIdx.z;
    const unsigned char* Xb = f8 + (size_t)PX[p] * BSZ * DIM;
    const unsigned char* Yb = f8 + (size_t)PY[p] * BSZ * DIM;
    float* rs = rowsum + p * BSZ;
    float* cs = colsum + p * BSZ;

    __shared__ __align__(16) unsigned char smem[65536];

    int tid  = threadIdx.x;
    int lane = tid & 63;
    int w    = tid >> 6;
    int wm = w >> 1, wn = w & 1;
    int q = lane >> 4, l = lane & 15;
    int bi = blockIdx.x * 128, bj = blockIdx.y * 128;

    // ---- stage both full-K panels (2048 16-B chunks each), XOR swizzle ----
    #pragma unroll
    for (int i = 0; i < 8; i++) {
        int sb  = i * 256 + w * 64;
        int s   = sb + lane;
        int row = s >> 4;
        int kq  = (s ^ row) & 15;
        async_cp16(smem + sb * 16,         Xb + (size_t)(bi + row) * 256 + kq * 16);
        async_cp16(smem + 32768 + sb * 16, Yb + (size_t)(bj + row) * 256 + kq * 16);
    }
    __syncthreads();  // single drain for the whole block

    // Hoisted fragment base addresses: Q = row*256 + qb + (((qh^row)&15)<<4)
    int qh = q >> 1, qb = (q & 1) * 8;
    unsigned qa[4], qbv[4];
    #pragma unroll
    for (int t = 0; t < 4; t++) {
        int ra = wm * 64 + t * 16 + l;
        int rb = wn * 64 + t * 16 + l;
        qa[t]  = (unsigned)(ra * 256 + qb + (((qh ^ ra) & 15) << 4));
        qbv[t] = (unsigned)(32768 + rb * 256 + qb + (((qh ^ rb) & 15) << 4));
    }

    floatx4 acc[4][4] = {};
    #pragma unroll
    for (int ks = 0; ks < 8; ks++) {
        const unsigned kx = (unsigned)(ks << 5);
        long long a[4], b[4];
        #pragma unroll
        for (int t = 0; t < 4; t++) {
            a[t] = *(const long long*)(smem + (qa[t] ^ kx));
            b[t] = *(const long long*)(smem + (qbv[t] ^ kx));
        }
        #pragma unroll
        for (int i = 0; i < 4; i++)
            #pragma unroll
            for (int j = 0; j < 4; j++)
                acc[i][j] = __builtin_amdgcn_mfma_f32_16x16x32_fp8_fp8(a[i], b[j], acc[i][j], 0, 0, 0);
    }

    // ---- epilogue: exp2 (raw v_exp_f32), butterfly reductions, atomics ----
    // C/D layout per 16x16 tile: col = l, row = q*4 + reg.
    #pragma unroll
    for (int ai = 0; ai < 4; ai++)
        #pragma unroll
        for (int bt = 0; bt < 4; bt++)
            #pragma unroll
            for (int r = 0; r < 4; r++)
                acc[ai][bt][r] = EXP2F(acc[ai][bt][r] - SC20L2E);

    // Row sums: v[t], t = ai*4+r, reduce over the 16 l-lanes; result t -> lane l==t.
    float v[16];
    #pragma unroll
    for (int ai = 0; ai < 4; ai++)
        #pragma unroll
        for (int r = 0; r < 4; r++)
            v[ai * 4 + r] = acc[ai][0][r] + acc[ai][1][r] + acc[ai][2][r] + acc[ai][3][r];

    float w1[8];
    #pragma unroll
    for (int k = 0; k < 8; k++) {
        float snd = (l & 1) ? v[2 * k] : v[2 * k + 1];
        float got = __shfl_xor(snd, 1, 64);
        w1[k] = ((l & 1) ? v[2 * k + 1] : v[2 * k]) + got;
    }
    float w2[4];
    #pragma unroll
    for (int m = 0; m < 4; m++) {
        float snd = ((l >> 1) & 1) ? w1[2 * m] : w1[2 * m + 1];
        float got = __shfl_xor(snd, 2, 64);
        w2[m] = (((l >> 1) & 1) ? w1[2 * m + 1] : w1[2 * m]) + got;
    }
    float w3[2];
    #pragma unroll
    for (int n = 0; n < 2; n++) {
        float snd = ((l >> 2) & 1) ? w2[2 * n] : w2[2 * n + 1];
        float got = __shfl_xor(snd, 4, 64);
        w3[n] = (((l >> 2) & 1) ? w2[2 * n + 1] : w2[2 * n]) + got;
    }
    {
        float snd = ((l >> 3) & 1) ? w3[0] : w3[1];
        float got = __shfl_xor(snd, 8, 64);
        float wr = (((l >> 3) & 1) ? w3[1] : w3[0]) + got;
        atomicAdd(&rs[bi + wm * 64 + ((l >> 2) << 4) + q * 4 + (l & 3)], wr);
    }

    // Col sums: c4[bt], reduce over the 4 q-groups; result bt -> q==bt.
    float c4[4];
    #pragma unroll
    for (int bt = 0; bt < 4; bt++) {
        float s = 0.f;
        #pragma unroll
        for (int ai = 0; ai < 4; ai++)
            #pragma unroll
            for (int r = 0; r < 4; r++) s += acc[ai][bt][r];
        c4[bt] = s;
    }
    float e0, e1, fsum;
    {
        float snd = (q & 1) ? c4[0] : c4[1];
        float got = __shfl_xor(snd, 16, 64);
        e0 = ((q & 1) ? c4[1] : c4[0]) + got;
    }
    {
        float snd = (q & 1) ? c4[2] : c4[3];
        float got = __shfl_xor(snd, 16, 64);
        e1 = ((q & 1) ? c4[3] : c4[2]) + got;
    }
    {
        float snd = ((q >> 1) & 1) ? e0 : e1;
        float got = __shfl_xor(snd, 32, 64);
        fsum = (((q >> 1) & 1) ? e1 : e0) + got;
    }
    atomicAdd(&cs[bj + wn * 64 + (q << 4) + l], fsum);
}

// total = [ sum over 4 pairs, 4096 rows of 0.5*(ln r + ln c) - d  + 20*4B ] / 2B
__global__ __launch_bounds__(1024)
void final_reduce_kernel(const float* __restrict__ rowsum,
                         const float* __restrict__ colsum,
                         const float* __restrict__ diag,
                         float* __restrict__ out) {
    __shared__ float red[1024];
    int tid = threadIdx.x;
    float acc = 0.f;
    #pragma unroll 4
    for (int idx = tid; idx < 4 * BSZ; idx += 1024)
        acc += 0.5f * (__logf(rowsum[idx]) + __logf(colsum[idx])) - diag[idx];
    red[tid] = acc;
    __syncthreads();
    for (int s = 512; s; s >>= 1) {
        if (tid < s) red[tid] += red[tid + s];
        __syncthreads();
    }
    if (tid == 0)
        out[0] = (red[0] + 20.0f * 4 * BSZ) / (BSZ * 2.0f);
}

extern "C" void kernel_launch(void* const* d_in, const int* in_sizes, int n_in,
                              void* d_out, int out_size, void* d_ws, size_t ws_size,
                              hipStream_t stream) {
    const float* in_anchor = (const float*)d_in[0];
    const float* in_pos    = (const float*)d_in[1];
    // d_in[2] (reference_anchor) intentionally unused, matching the reference.
    const float* in_rtext  = (const float*)d_in[3];
    const float* in_rvis   = (const float*)d_in[4];

    char* ws = (char*)d_ws;
    unsigned char* f8 = (unsigned char*)ws;                 // 4 * B * D fp8
    size_t f8_bytes = (size_t)4 * BSZ * DIM;
    float* rowsum = (float*)(ws + f8_bytes);                // 4 * B
    float* colsum = rowsum + 4 * BSZ;                       // 4 * B
    float* diag   = colsum + 4 * BSZ;                       // 4 * B

    prep_kernel<<<BSZ / 4, 256, 0, stream>>>(
        in_anchor, in_pos, in_rtext, in_rvis, f8, diag, rowsum, colsum);

    pair_scores_kernel<<<dim3(BSZ / 128, BSZ / 128, 4), 256, 0, stream>>>(
        f8, rowsum, colsum);

    final_reduce_kernel<<<1, 1024, 0, stream>>>(rowsum, colsum, diag, (float*)d_out);
}